// Round 1
// baseline (388.226 us; speedup 1.0000x reference)
//
#include <hip/hip_runtime.h>

#define DD 160
#define HH 192
#define WW 160
#define VOL (DD * HH * WW)   // 4915200
#define NB 2
#define NC 2

__global__ __launch_bounds__(256) void warp_kernel(
    const float* __restrict__ x,
    const float* __restrict__ flow,
    float* __restrict__ out)
{
    int i = blockIdx.x * blockDim.x + threadIdx.x;
    if (i >= NB * VOL) return;

    int b = (i >= VOL) ? 1 : 0;
    int v = i - b * VOL;

    int xw = v % WW;
    int t  = v / WW;
    int yh = t % HH;
    int zd = t / HH;

    const float* fb = flow + (size_t)b * 3 * VOL;
    float pz = (float)zd + fb[v];
    float py = (float)yh + fb[v + VOL];
    float px = (float)xw + fb[v + 2 * VOL];

    float z0f = floorf(pz), y0f = floorf(py), x0f = floorf(px);
    float fz = pz - z0f, fy = py - y0f, fx = px - x0f;
    int z0 = (int)z0f, y0 = (int)y0f, x0 = (int)x0f;
    int z1 = z0 + 1,  y1 = y0 + 1,  x1 = x0 + 1;

    float wz0 = 1.0f - fz, wz1 = fz;
    float wy0 = 1.0f - fy, wy1 = fy;
    float wx0 = 1.0f - fx, wx1 = fx;

    // zeros padding: zero the weight if OOB, clamp the index for the gather
    wz0 = (z0 >= 0 && z0 < DD) ? wz0 : 0.0f;
    wz1 = (z1 >= 0 && z1 < DD) ? wz1 : 0.0f;
    wy0 = (y0 >= 0 && y0 < HH) ? wy0 : 0.0f;
    wy1 = (y1 >= 0 && y1 < HH) ? wy1 : 0.0f;
    wx0 = (x0 >= 0 && x0 < WW) ? wx0 : 0.0f;
    wx1 = (x1 >= 0 && x1 < WW) ? wx1 : 0.0f;

    int z0c = min(max(z0, 0), DD - 1);
    int z1c = min(max(z1, 0), DD - 1);
    int y0c = min(max(y0, 0), HH - 1);
    int y1c = min(max(y1, 0), HH - 1);
    int x0c = min(max(x0, 0), WW - 1);
    int x1c = min(max(x1, 0), WW - 1);

    int p00 = (z0c * HH + y0c) * WW;
    int p01 = (z0c * HH + y1c) * WW;
    int p10 = (z1c * HH + y0c) * WW;
    int p11 = (z1c * HH + y1c) * WW;

    int i000 = p00 + x0c, i001 = p00 + x1c;
    int i010 = p01 + x0c, i011 = p01 + x1c;
    int i100 = p10 + x0c, i101 = p10 + x1c;
    int i110 = p11 + x0c, i111 = p11 + x1c;

    float w000 = wz0 * wy0 * wx0;
    float w001 = wz0 * wy0 * wx1;
    float w010 = wz0 * wy1 * wx0;
    float w011 = wz0 * wy1 * wx1;
    float w100 = wz1 * wy0 * wx0;
    float w101 = wz1 * wy0 * wx1;
    float w110 = wz1 * wy1 * wx0;
    float w111 = wz1 * wy1 * wx1;

    const float* xb0 = x + (size_t)b * NC * VOL;
    const float* xb1 = xb0 + VOL;

    float acc0 = w000 * xb0[i000] + w001 * xb0[i001]
               + w010 * xb0[i010] + w011 * xb0[i011]
               + w100 * xb0[i100] + w101 * xb0[i101]
               + w110 * xb0[i110] + w111 * xb0[i111];

    float acc1 = w000 * xb1[i000] + w001 * xb1[i001]
               + w010 * xb1[i010] + w011 * xb1[i011]
               + w100 * xb1[i100] + w101 * xb1[i101]
               + w110 * xb1[i110] + w111 * xb1[i111];

    float* ob = out + (size_t)b * NC * VOL;
    ob[v]       = acc0;
    ob[v + VOL] = acc1;
}

extern "C" void kernel_launch(void* const* d_in, const int* in_sizes, int n_in,
                              void* d_out, int out_size, void* d_ws, size_t ws_size,
                              hipStream_t stream) {
    const float* x    = (const float*)d_in[0];
    const float* flow = (const float*)d_in[1];
    float* out        = (float*)d_out;

    int total = NB * VOL;                 // 9,830,400 threads
    int block = 256;
    int grid  = (total + block - 1) / block;
    warp_kernel<<<grid, block, 0, stream>>>(x, flow, out);
}